// Round 1
// baseline (2660.126 us; speedup 1.0000x reference)
//
#include <hip/hip_runtime.h>
#include <hip/hip_bf16.h>
#include <math.h>

typedef short short8 __attribute__((ext_vector_type(8)));
typedef short short4v __attribute__((ext_vector_type(4)));
typedef float f32x4 __attribute__((ext_vector_type(4)));
typedef unsigned short ushort_t;
typedef unsigned int uint_t;

#define D_MODEL 768
#define L_LAYERS 6
#define N_TOK 4096   // B*T
#define T_SEQ 2048
#define H_HEADS 12
#define V_VOCAB 32000
#define L2E 1.44269504088896340736f

// ---------- helpers ----------
__device__ __forceinline__ ushort_t f2b(float f) {
  uint_t u = __builtin_bit_cast(uint_t, f);
  u += 0x7fffu + ((u >> 16) & 1u);   // RNE
  return (ushort_t)(u >> 16);
}

__device__ __forceinline__ void gload_lds16(const void* g, void* l) {
  __builtin_amdgcn_global_load_lds(
      (const __attribute__((address_space(1))) unsigned int*)g,
      (__attribute__((address_space(3))) unsigned int*)l, 16, 0, 0);
}

// ---------- embedding ----------
__global__ void embed_kernel(const int* __restrict__ idx, const float* __restrict__ tok,
                             const float* __restrict__ pos, float* __restrict__ x) {
  int n = blockIdx.x;
  int tok_id = idx[n];
  int t = n & (T_SEQ - 1);
  const float* tr = tok + (size_t)tok_id * D_MODEL;
  const float* pr = pos + (size_t)t * D_MODEL;
  float* xr = x + (size_t)n * D_MODEL;
  for (int k = threadIdx.x; k < D_MODEL; k += 256) xr[k] = tr[k] + pr[k];
}

// ---------- layernorm (fp32 in -> bf16 out) ----------
__global__ void ln_kernel(const float* __restrict__ x, const float* __restrict__ w,
                          const float* __restrict__ b, ushort_t* __restrict__ out) {
  int r = blockIdx.x, tid = threadIdx.x;
  const float* xr = x + (size_t)r * D_MODEL;
  float v0 = xr[tid], v1 = xr[tid + 256], v2 = xr[tid + 512];
  __shared__ float red[8];
  int l = tid & 63, wv = tid >> 6;
  float s = v0 + v1 + v2;
#pragma unroll
  for (int m = 32; m >= 1; m >>= 1) s += __shfl_xor(s, m, 64);
  if (l == 0) red[wv] = s;
  __syncthreads();
  float mean = (red[0] + red[1] + red[2] + red[3]) * (1.f / 768.f);
  float t0 = v0 - mean, t1 = v1 - mean, t2 = v2 - mean;
  float sq = t0 * t0 + t1 * t1 + t2 * t2;
#pragma unroll
  for (int m = 32; m >= 1; m >>= 1) sq += __shfl_xor(sq, m, 64);
  if (l == 0) red[4 + wv] = sq;
  __syncthreads();
  float var = (red[4] + red[5] + red[6] + red[7]) * (1.f / 768.f);
  float rstd = rsqrtf(var + 1e-5f);
  ushort_t* orow = out + (size_t)r * D_MODEL;
  orow[tid]       = f2b(t0 * rstd * w[tid] + b[tid]);
  orow[tid + 256] = f2b(t1 * rstd * w[tid + 256] + b[tid + 256]);
  orow[tid + 512] = f2b(t2 * rstd * w[tid + 512] + b[tid + 512]);
}

// ---------- weight transpose + cast fp32[R,C] -> bf16[C,R], per-layer via z ----------
__global__ void transpose_cast_kernel(const float* __restrict__ in, ushort_t* __restrict__ out,
                                      int R, int C) {
  __shared__ float tile[32][33];
  size_t zoff = (size_t)blockIdx.z * R * C;
  in += zoff; out += zoff;
  int c0 = blockIdx.x * 32, r0 = blockIdx.y * 32;
  int tx = threadIdx.x, ty = threadIdx.y;  // blockDim (32,8)
#pragma unroll
  for (int i = 0; i < 4; i++)
    tile[ty + i * 8][tx] = in[(size_t)(r0 + ty + i * 8) * C + (c0 + tx)];
  __syncthreads();
#pragma unroll
  for (int i = 0; i < 4; i++)
    out[(size_t)(c0 + ty + i * 8) * R + (r0 + tx)] = f2b(tile[tx][ty + i * 8]);
}

// ---------- plain cast fp32 -> bf16 ----------
__global__ void cast_kernel(const float* __restrict__ in, ushort_t* __restrict__ out, int n) {
  for (int i = blockIdx.x * 256 + threadIdx.x; i < n; i += gridDim.x * 256)
    out[i] = f2b(in[i]);
}

// ---------- bf16 NT GEMM: C[M,N] = A[M,K] * B[N,K]^T, 128x128 tile, BK=32 ----------
#define EPI_STORE 0
#define EPI_ADD 1
#define EPI_GELU 2
#define EPI_CASTB 3

template <int EPI>
__global__ __launch_bounds__(256) void gemm_nt(const ushort_t* __restrict__ A,
                                               const ushort_t* __restrict__ B,
                                               float* __restrict__ Cf,
                                               ushort_t* __restrict__ Cb,
                                               int M, int N, int K) {
  __shared__ __align__(16) ushort_t As[128 * 32];
  __shared__ __align__(16) ushort_t Bs[128 * 32];
  int t = threadIdx.x;
  int l = t & 63, wv = t >> 6;
  int wm = (wv >> 1) * 64, wn = (wv & 1) * 64;

  // XCD-aware bijective swizzle (m204): contiguous wg chunks per XCD for L2 reuse
  int nwg = gridDim.x * gridDim.y;
  int bid = blockIdx.y * gridDim.x + blockIdx.x;
  int qn = nwg >> 3, r8 = nwg & 7;
  int xcd = bid & 7, pos = bid >> 3;
  int wg = (xcd < r8 ? xcd * (qn + 1) : r8 * (qn + 1) + (xcd - r8) * qn) + pos;
  int bn = wg % gridDim.x, bm = wg / gridDim.x;

  int fr = l & 15, fq = l >> 4;

  int srow = t >> 2;         // 0..63
  int scol = (t & 3) * 8;    // bf16 elems within 32-wide K tile
  const ushort_t* gA = A + (size_t)(bm * 128 + srow) * K + scol;
  const ushort_t* gB = B + (size_t)(bn * 128 + srow) * K + scol;
  ushort_t* lA0 = &As[(wv * 16) * 32];
  ushort_t* lA1 = &As[(64 + wv * 16) * 32];
  ushort_t* lB0 = &Bs[(wv * 16) * 32];
  ushort_t* lB1 = &Bs[(64 + wv * 16) * 32];

  f32x4 acc[4][4];
#pragma unroll
  for (int i = 0; i < 4; i++)
#pragma unroll
    for (int j = 0; j < 4; j++) acc[i][j] = (f32x4){0.f, 0.f, 0.f, 0.f};

  for (int kt = 0; kt < K; kt += 32) {
    gload_lds16(gA + kt, lA0);
    gload_lds16(gA + (size_t)64 * K + kt, lA1);
    gload_lds16(gB + kt, lB0);
    gload_lds16(gB + (size_t)64 * K + kt, lB1);
    __syncthreads();
    short8 af[4], bf[4];
#pragma unroll
    for (int i = 0; i < 4; i++)
      af[i] = *(const short8*)&As[(wm + i * 16 + fr) * 32 + fq * 8];
#pragma unroll
    for (int j = 0; j < 4; j++)
      bf[j] = *(const short8*)&Bs[(wn + j * 16 + fr) * 32 + fq * 8];
#pragma unroll
    for (int i = 0; i < 4; i++)
#pragma unroll
      for (int j = 0; j < 4; j++)
        acc[i][j] = __builtin_amdgcn_mfma_f32_16x16x32_bf16(af[i], bf[j], acc[i][j], 0, 0, 0);
    __syncthreads();
  }

  // C/D layout: col = lane&15, row = (lane>>4)*4 + reg
  int row0 = bm * 128 + wm + fq * 4;
  int col0 = bn * 128 + wn + fr;
#pragma unroll
  for (int i = 0; i < 4; i++) {
#pragma unroll
    for (int j = 0; j < 4; j++) {
#pragma unroll
      for (int r = 0; r < 4; r++) {
        int row = row0 + i * 16 + r;
        int col = col0 + j * 16;
        size_t off = (size_t)row * N + col;
        float v = acc[i][j][r];
        if (EPI == EPI_STORE) {
          Cf[off] = v;
        } else if (EPI == EPI_ADD) {
          Cf[off] += v;
        } else if (EPI == EPI_GELU) {  // exact GELU -> bf16
          Cb[off] = f2b(0.5f * v * (1.f + erff(v * 0.70710678118f)));
        } else {  // EPI_CASTB: plain bf16 store
          Cb[off] = f2b(v);
        }
      }
    }
  }
}

// ---------- MFMA flash attention, bf16 ----------
// Block = one (b,h) x 64 query rows. 4 waves x 16 rows. KV tiles of 64.
// Swapped QK^T: s = mfma(Kfrag, Qfrag) -> S^T tile, lane holds [key=kb*16+kg*4+r][q=ql].
// Softmax row (q=ql) is lane-local in ql; reduce across kg via shfl_xor 16/32.
// PV: O^T = V^T . P^T : o = mfma(Vt_frag, Pfrag). P exchanged in-register (2-pass shfl).
// LDS tiles Ks/Vt: [row][64] bf16, 16B-chunk XOR swizzle chunk^=(row&7) -> b128 reads at
// the 2-way (free) aliasing floor.
__global__ __launch_bounds__(256) void attn_mfma(const ushort_t* __restrict__ qkv,
                                                 ushort_t* __restrict__ y) {
  __shared__ __align__(16) ushort_t Ks[64 * 64];  // [key][d] swizzled
  __shared__ __align__(16) ushort_t Vt[64 * 64];  // [d][key] swizzled

  int id = blockIdx.x;
  int bh = id % 24;
  int qb = 31 - id / 24;            // biggest tiles dispatch first
  int b = bh / H_HEADS, h = bh % H_HEADS;
  int t = threadIdx.x, l = t & 63, w = t >> 6;
  int ql = l & 15, kg = l >> 4;
  int q0 = qb * 64;
  size_t base = (size_t)b * T_SEQ * 2304;
  int qrow = q0 + w * 16 + ql;      // this lane's softmax row

  // Q as B-fragment (col = q = ql), k = d : two 32-wide halves
  const ushort_t* qptr = qkv + base + (size_t)qrow * 2304 + h * 64 + kg * 8;
  short8 qf0 = *(const short8*)qptr;
  short8 qf1 = *(const short8*)(qptr + 32);

  float mrun = -INFINITY, lrun = 0.f;
  f32x4 o[4];
#pragma unroll
  for (int jd = 0; jd < 4; jd++) o[jd] = (f32x4){0.f, 0.f, 0.f, 0.f};

  const ushort_t* kbase = qkv + base + 768 + h * 64;
  const ushort_t* vbase = qkv + base + 1536 + h * 64;

  for (int kt = 0; kt <= q0; kt += 64) {
    // ---- stage K tile [key][d] and V^T tile [d][key], chunk-XOR swizzled ----
#pragma unroll
    for (int i = 0; i < 2; i++) {
      int c = i * 256 + t;            // 512 short8 chunks per tile
      int key = c >> 3, dc = c & 7;   // K: row=key, 8-d chunk dc
      short8 k8 = *(const short8*)(kbase + (size_t)(kt + key) * 2304 + dc * 8);
      *(short8*)&Ks[key * 64 + ((dc ^ (key & 7)) * 8)] = k8;
      int vd0 = dc * 8;               // V: same source decomposition
      short8 v8 = *(const short8*)(vbase + (size_t)(kt + key) * 2304 + vd0);
#pragma unroll
      for (int e = 0; e < 8; e++) {
        int d = vd0 + e;
        Vt[d * 64 + (((key >> 3) ^ (d & 7)) * 8) + (key & 7)] = (ushort_t)v8[e];
      }
    }
    __syncthreads();

    // ---- swapped QK^T: S^T[key][q], scaled ----
    f32x4 s[4];
#pragma unroll
    for (int kb = 0; kb < 4; kb++) {
      s[kb] = (f32x4){0.f, 0.f, 0.f, 0.f};
      short8 kfa = *(const short8*)&Ks[(kb * 16 + ql) * 64 + ((kg ^ (ql & 7)) * 8)];
      s[kb] = __builtin_amdgcn_mfma_f32_16x16x32_bf16(kfa, qf0, s[kb], 0, 0, 0);
      short8 kfb = *(const short8*)&Ks[(kb * 16 + ql) * 64 + (((kg + 4) ^ (ql & 7)) * 8)];
      s[kb] = __builtin_amdgcn_mfma_f32_16x16x32_bf16(kfb, qf1, s[kb], 0, 0, 0);
    }
#pragma unroll
    for (int kb = 0; kb < 4; kb++)
#pragma unroll
      for (int r = 0; r < 4; r++) s[kb][r] *= 0.125f;

    // causal mask (only the diagonal tile; block-uniform branch)
    if (kt == q0) {
      int qloc = w * 16 + ql;
#pragma unroll
      for (int kb = 0; kb < 4; kb++)
#pragma unroll
        for (int r = 0; r < 4; r++) {
          int keyloc = kb * 16 + kg * 4 + r;
          if (keyloc > qloc) s[kb][r] = -INFINITY;
        }
    }

    // ---- online softmax (row = q = ql; reduce across kg lanes) ----
    float pm = -INFINITY;
#pragma unroll
    for (int kb = 0; kb < 4; kb++)
#pragma unroll
      for (int r = 0; r < 4; r++) pm = fmaxf(pm, s[kb][r]);
    pm = fmaxf(pm, __shfl_xor(pm, 16, 64));
    pm = fmaxf(pm, __shfl_xor(pm, 32, 64));
    float mnew = fmaxf(mrun, pm);
    float ps = 0.f;
#pragma unroll
    for (int kb = 0; kb < 4; kb++)
#pragma unroll
      for (int r = 0; r < 4; r++) {
        float p = exp2f((s[kb][r] - mnew) * L2E);
        s[kb][r] = p;
        ps += p;
      }
    ps += __shfl_xor(ps, 16, 64);
    ps += __shfl_xor(ps, 32, 64);
    float alpha = exp2f((mrun - mnew) * L2E);
    lrun = lrun * alpha + ps;
    mrun = mnew;
#pragma unroll
    for (int jd = 0; jd < 4; jd++)
#pragma unroll
      for (int r = 0; r < 4; r++) o[jd][r] *= alpha;

    // ---- P exchange (C-layout -> B-fragment) + PV MFMA per 32-key half ----
    // dest lane (ql,kg) elem e=4*eb+r needs P from lane (ql, 2*(kg&1)+eb),
    // reg s[2*h2 + (kg>>1)][r]  -> two shfl passes + select.
#pragma unroll
    for (int h2 = 0; h2 < 2; h2++) {
      short8 pb;
#pragma unroll
      for (int e = 0; e < 8; e++) {
        int r = e & 3, eb = e >> 2;
        int src = ql + 16 * (2 * (kg & 1) + eb);
        float vA = __shfl(s[2 * h2][r], src, 64);
        float vB = __shfl(s[2 * h2 + 1][r], src, 64);
        float v = (kg >> 1) ? vB : vA;
        pb[e] = (short)f2b(v);
      }
#pragma unroll
      for (int jd = 0; jd < 4; jd++) {
        short8 vf = *(const short8*)&Vt[(jd * 16 + ql) * 64 + (((kg + 4 * h2) ^ (ql & 7)) * 8)];
        o[jd] = __builtin_amdgcn_mfma_f32_16x16x32_bf16(vf, pb, o[jd], 0, 0, 0);
      }
    }
    __syncthreads();
  }

  // ---- epilogue: O^T regs (row=d=jd*16+kg*4+r, col=q=ql) -> y[token][768] bf16 ----
  float inv = 1.f / lrun;
  size_t yb = (size_t)(b * T_SEQ + qrow) * D_MODEL + h * 64;
#pragma unroll
  for (int jd = 0; jd < 4; jd++) {
    short4v pk;
#pragma unroll
    for (int r = 0; r < 4; r++) pk[r] = (short)f2b(o[jd][r] * inv);
    *(short4v*)&y[yb + jd * 16 + kg * 4] = pk;
  }
}

// ---------- launch ----------
extern "C" void kernel_launch(void* const* d_in, const int* in_sizes, int n_in,
                              void* d_out, int out_size, void* d_ws, size_t ws_size,
                              hipStream_t stream) {
  const int*   idx     = (const int*)d_in[0];
  const float* tok_emb = (const float*)d_in[1];
  const float* pos_emb = (const float*)d_in[2];
  const float* ln1_w   = (const float*)d_in[3];
  const float* ln1_b   = (const float*)d_in[4];
  const float* qkv_w   = (const float*)d_in[5];
  const float* out_w   = (const float*)d_in[6];
  const float* ln2_w   = (const float*)d_in[7];
  const float* ln2_b   = (const float*)d_in[8];
  const float* ff1_w   = (const float*)d_in[9];
  const float* ff2_w   = (const float*)d_in[10];
  const float* lnf_w   = (const float*)d_in[11];
  const float* lnf_b   = (const float*)d_in[12];
  float* out = (float*)d_out;

  // workspace layout
  char* ws = (char*)d_ws;
  ushort_t* WqkvT = (ushort_t*)ws; ws += (size_t)L_LAYERS * 2304 * 768 * 2;
  ushort_t* WoutT = (ushort_t*)ws; ws += (size_t)L_LAYERS * 768 * 768 * 2;
  ushort_t* W1T   = (ushort_t*)ws; ws += (size_t)L_LAYERS * 3072 * 768 * 2;
  ushort_t* W2T   = (ushort_t*)ws; ws += (size_t)L_LAYERS * 768 * 3072 * 2;
  ushort_t* EmbB  = (ushort_t*)ws; ws += (size_t)V_VOCAB * 768 * 2;
  float*    x     = (float*)ws;    ws += (size_t)N_TOK * 768 * 4;
  ushort_t* hbuf  = (ushort_t*)ws; ws += (size_t)N_TOK * 768 * 2;
  ushort_t* qkvb  = (ushort_t*)ws; ws += (size_t)N_TOK * 2304 * 2;
  ushort_t* ybuf  = (ushort_t*)ws; ws += (size_t)N_TOK * 768 * 2;
  ushort_t* abuf  = (ushort_t*)ws; ws += (size_t)N_TOK * 3072 * 2;

  dim3 tb(32, 8);
  transpose_cast_kernel<<<dim3(2304 / 32, 768 / 32, 6), tb, 0, stream>>>(qkv_w, WqkvT, 768, 2304);
  transpose_cast_kernel<<<dim3(768 / 32, 768 / 32, 6), tb, 0, stream>>>(out_w, WoutT, 768, 768);
  transpose_cast_kernel<<<dim3(3072 / 32, 768 / 32, 6), tb, 0, stream>>>(ff1_w, W1T, 768, 3072);
  transpose_cast_kernel<<<dim3(768 / 32, 3072 / 32, 6), tb, 0, stream>>>(ff2_w, W2T, 3072, 768);
  cast_kernel<<<12000, 256, 0, stream>>>(tok_emb, EmbB, V_VOCAB * 768);
  embed_kernel<<<N_TOK, 256, 0, stream>>>(idx, tok_emb, pos_emb, x);

  for (int layer = 0; layer < L_LAYERS; layer++) {
    ln_kernel<<<N_TOK, 256, 0, stream>>>(x, ln1_w + layer * 768, ln1_b + layer * 768, hbuf);
    gemm_nt<EPI_CASTB><<<dim3(2304 / 128, N_TOK / 128), 256, 0, stream>>>(
        hbuf, WqkvT + (size_t)layer * 2304 * 768, nullptr, qkvb, N_TOK, 2304, 768);
    attn_mfma<<<24 * 32, 256, 0, stream>>>(qkvb, ybuf);
    gemm_nt<EPI_ADD><<<dim3(768 / 128, N_TOK / 128), 256, 0, stream>>>(
        ybuf, WoutT + (size_t)layer * 768 * 768, x, nullptr, N_TOK, 768, 768);
    ln_kernel<<<N_TOK, 256, 0, stream>>>(x, ln2_w + layer * 768, ln2_b + layer * 768, hbuf);
    gemm_nt<EPI_GELU><<<dim3(3072 / 128, N_TOK / 128), 256, 0, stream>>>(
        hbuf, W1T + (size_t)layer * 3072 * 768, nullptr, abuf, N_TOK, 3072, 768);
    gemm_nt<EPI_ADD><<<dim3(768 / 128, N_TOK / 128), 256, 0, stream>>>(
        abuf, W2T + (size_t)layer * 768 * 3072, x, nullptr, N_TOK, 768, 3072);
  }
  ln_kernel<<<N_TOK, 256, 0, stream>>>(x, lnf_w, lnf_b, hbuf);
  gemm_nt<EPI_STORE><<<dim3(V_VOCAB / 128, N_TOK / 128), 256, 0, stream>>>(
      hbuf, EmbB, out, nullptr, N_TOK, V_VOCAB, 768);
}